// Round 5
// baseline (2875.652 us; speedup 1.0000x reference)
//
#include <hip/hip_runtime.h>
#include <math.h>

// GraphNet: 2x EdgeConv (E=800k, F=H=64) + BN folded/commuted + pooling.
// R5: latency attack. (a) sorted edges materialized as int2 epair (no
// eord->esrc/edst double-hop); (b) depth-1 software pipeline in all edge
// passes: next tile's epair + x-gathers prefetched into registers while the
// current tile computes (T14 async-stage split); dst via intra-wave shfl.

typedef unsigned short u16;
typedef unsigned int   u32;
typedef __bf16 bf16x8 __attribute__((ext_vector_type(8)));
typedef float  f32x4  __attribute__((ext_vector_type(4)));
typedef unsigned short us4 __attribute__((ext_vector_type(4)));

#define EPSBN 1e-5f

// param block layout (floats):
// 0:stS1a[128] 128:stQ1a[128] 256:stS1b[64] 320:stQ1b[64] 384:stS2[64] 448:stQ2[64]
// 512:s1a[128] 640:t1a[128] 768:b1bF[64] 832:s1b[64] 896:t1b[64] 960:s2[64] 1024:t2[64]
// 1088:gmax[4096] 5184:gsum[4096] 9280:cnt[64]  total 9344
#define PB_TOT 9344

__device__ __forceinline__ u32 f2bf1(float f){
    u32 u = __float_as_uint(f);
    return (u + 0x7FFFu + ((u >> 16) & 1u)) >> 16;
}
__device__ __forceinline__ float bf2f(u16 b){
    return __uint_as_float(((u32)b) << 16);
}
__device__ __forceinline__ u32 bsub2(u32 xj, u32 xi){
    float jl = __uint_as_float(xj << 16), jh = __uint_as_float(xj & 0xFFFF0000u);
    float il = __uint_as_float(xi << 16), ih = __uint_as_float(xi & 0xFFFF0000u);
    u32 lo = f2bf1(jl - il), hi = f2bf1(jh - ih);
    return lo | (hi << 16);
}
__device__ __forceinline__ void atomicMaxF(float* a, float v){
    if (v >= 0.f) atomicMax((int*)a, __float_as_int(v));
    else          atomicMin((u32*)a, __float_as_uint(v));
}
// XOR swizzle: permutes 8-elem (16B) blocks within a 128-elem row -> ds_read_b128
__device__ __forceinline__ int swz(int row, int k){
    return row*128 + (k ^ ((row & 7) << 3));
}
__device__ __forceinline__ f32x4 mfma16(bf16x8 a, bf16x8 b, f32x4 c){
    return __builtin_amdgcn_mfma_f32_16x16x32_bf16(a, b, c, 0, 0, 0);
}

// Segment-run merge masks over a 16-lane group. ALL shuffles unconditional
// (straight-line, all lanes active); guards applied after (R4 lesson).
struct SegMasks { bool head, m1, m2, m4, m8; };
__device__ __forceinline__ SegMasks seg_masks(int dL, int lr){
    int dUp = __shfl_up(dL, 1, 16);
    int d1  = __shfl_down(dL, 1, 16);
    int d2  = __shfl_down(dL, 2, 16);
    int d4  = __shfl_down(dL, 4, 16);
    int d8  = __shfl_down(dL, 8, 16);
    SegMasks s;
    s.head = (lr == 0) || (dUp != dL);
    s.m1 = (lr + 1 < 16) && (d1 == dL);
    s.m2 = (lr + 2 < 16) && (d2 == dL);
    s.m4 = (lr + 4 < 16) && (d4 == dL);
    s.m8 = (lr + 8 < 16) && (d8 == dL);
    return s;
}
__device__ __forceinline__ float seg_max(float v, const SegMasks& s){
    float t1 = __shfl_down(v, 1, 16); if (s.m1) v = fmaxf(v, t1);
    float t2 = __shfl_down(v, 2, 16); if (s.m2) v = fmaxf(v, t2);
    float t4 = __shfl_down(v, 4, 16); if (s.m4) v = fmaxf(v, t4);
    float t8 = __shfl_down(v, 8, 16); if (s.m8) v = fmaxf(v, t8);
    return v;
}

// Prefetch registers for one tile: each lane holds a quarter (32B) of x[dst]
// and x[src] for edge (lane>>2) of its wave, plus that edge's dst index.
struct Pref { uint4 xi0, xi1, xj0, xj1; int dstS; };

__device__ __forceinline__ void load_tile(Pref& p, const u16* __restrict__ xb,
                                          const int2* __restrict__ ep,
                                          int t, int wave, int lane, int E){
    int eS = t*64 + wave*16 + (lane >> 2);
    if (eS < E){
        int2 sd = ep[eS];
        p.dstS = sd.y;
        int part = lane & 3;
        const uint4* pi = (const uint4*)(xb + (size_t)sd.y*64 + part*16);
        const uint4* pj = (const uint4*)(xb + (size_t)sd.x*64 + part*16);
        p.xi0 = pi[0]; p.xi1 = pi[1];
        p.xj0 = pj[0]; p.xj1 = pj[1];
    } else {
        uint4 z; z.x = z.y = z.z = z.w = 0u;
        p.xi0 = p.xi1 = p.xj0 = p.xj1 = z;
        p.dstS = -2;
    }
}

// Stage prefetched tile into At (wave-own rows only -> no barrier needed).
// At[edge][0:64]=x[dst], At[edge][64:128]=x[src]-x[dst]  (bf16, swizzled)
__device__ __forceinline__ void write_At(u16* At, const Pref& p, int wave, int lane){
    int part = lane & 3;
    int arow = wave*16 + (lane >> 2);
    *(uint4*)&At[swz(arow, part*16)]     = p.xi0;
    *(uint4*)&At[swz(arow, part*16+8)]   = p.xi1;
    uint4 e0, e1;
    e0.x = bsub2(p.xj0.x, p.xi0.x); e0.y = bsub2(p.xj0.y, p.xi0.y);
    e0.z = bsub2(p.xj0.z, p.xi0.z); e0.w = bsub2(p.xj0.w, p.xi0.w);
    e1.x = bsub2(p.xj1.x, p.xi1.x); e1.y = bsub2(p.xj1.y, p.xi1.y);
    e1.z = bsub2(p.xj1.z, p.xi1.z); e1.w = bsub2(p.xj1.w, p.xi1.w);
    *(uint4*)&At[swz(arow, 64+part*16)]   = e0;
    *(uint4*)&At[swz(arow, 64+part*16+8)] = e1;
}

__global__ void k_init(const float* __restrict__ x, u16* __restrict__ xb,
                       float* __restrict__ agg,
                       float* __restrict__ pblk, int* __restrict__ deg,
                       int NF, int N){
    int i = blockIdx.x*256 + threadIdx.x;
    if (i < NF){
        xb[i] = (u16)f2bf1(x[i]);
        agg[i] = -INFINITY;
    }
    if (i < N) deg[i] = 0;
    if (i < PB_TOT){
        pblk[i] = (i >= 1088 && i < 5184) ? -INFINITY : 0.f;
    }
}

__global__ void k_hist(const int* __restrict__ edst, int* __restrict__ deg, int E){
    int e = blockIdx.x*256 + threadIdx.x;
    if (e < E) atomicAdd(&deg[edst[e]], 1);
}

// single-block exclusive scan of deg[0..N) -> cursor[0..N)
__global__ __launch_bounds__(1024) void k_scan(const int* __restrict__ deg,
                                               int* __restrict__ cursor, int N){
    __shared__ int buf[1024];
    __shared__ int carry;
    int tid = threadIdx.x;
    if (tid == 0) carry = 0;
    __syncthreads();
    for (int base = 0; base < N; base += 1024){
        int i = base + tid;
        int v = (i < N) ? deg[i] : 0;
        buf[tid] = v;
        __syncthreads();
        #pragma unroll
        for (int s = 1; s < 1024; s <<= 1){
            int a = (tid >= s) ? buf[tid - s] : 0;
            __syncthreads();
            buf[tid] += a;
            __syncthreads();
        }
        int inc = buf[tid] + carry;
        if (i < N) cursor[i] = inc - v;
        __syncthreads();
        if (tid == 1023) carry = inc;
        __syncthreads();
    }
}

__global__ void k_scatter(const int* __restrict__ esrc, const int* __restrict__ edst,
                          int* __restrict__ cursor, int2* __restrict__ ep, int E){
    int e = blockIdx.x*256 + threadIdx.x;
    if (e < E){
        int d = edst[e];
        int pos = atomicAdd(&cursor[d], 1);
        ep[pos] = make_int2(esrc[e], d);
    }
}

__global__ __launch_bounds__(256) void k_pass1(
    const u16* __restrict__ xb, const int2* __restrict__ ep,
    const float* __restrict__ W1a, const float* __restrict__ b1a,
    float* __restrict__ pblk, int E, int nTiles)
{
    __shared__ u16 Wt[128*128];   // Wt[n][k] = W1a[k][n] (bf16, swizzled)
    __shared__ u16 At[64*128];
    int tid = threadIdx.x;
    for (int i = tid; i < 128*128; i += 256){
        int k = i >> 7, n = i & 127;
        Wt[swz(n, k)] = (u16)f2bf1(W1a[i]);
    }
    __syncthreads();
    int lane = tid & 63, wave = tid >> 6;
    int lg = lane >> 4, lr = lane & 15;
    const float4* Bv = (const float4*)b1a;
    float runS[32], runQ[32];
    #pragma unroll
    for (int i = 0; i < 32; i++){ runS[i] = 0.f; runQ[i] = 0.f; }

    int t = blockIdx.x;
    Pref p;
    load_tile(p, xb, ep, t, wave, lane, E);
    for (; t < nTiles; t += gridDim.x){
        int tn = t + gridDim.x;
        Pref pn;
        if (tn < nTiles) load_tile(pn, xb, ep, tn, wave, lane, E);
        write_At(At, p, wave, lane);
        int row = wave*16 + lr;
        bf16x8 bfr[4];
        #pragma unroll
        for (int kt = 0; kt < 4; kt++)
            bfr[kt] = *(const bf16x8*)&At[swz(row, kt*32 + lg*8)];
        bool ev = (t*64 + wave*16 + lr) < E;
        #pragma unroll
        for (int mt = 0; mt < 8; mt++){
            f32x4 acc = {0.f,0.f,0.f,0.f};
            #pragma unroll
            for (int kt = 0; kt < 4; kt++){
                bf16x8 af = *(const bf16x8*)&Wt[swz(mt*16 + lr, kt*32 + lg*8)];
                acc = mfma16(af, bfr[kt], acc);
            }
            if (ev){
                float4 bb = Bv[mt*4 + lg];
                const float* bbp = (const float*)&bb;
                #pragma unroll
                for (int j = 0; j < 4; j++){
                    float h = fmaxf(acc[j] + bbp[j], 0.f);
                    runS[mt*4+j] += h;
                    runQ[mt*4+j] = fmaf(h, h, runQ[mt*4+j]);
                }
            }
        }
        if (tn < nTiles) p = pn;
    }
    #pragma unroll
    for (int i = 0; i < 32; i++){
        float s = runS[i], q = runQ[i];
        #pragma unroll
        for (int m = 1; m < 16; m <<= 1){ s += __shfl_xor(s, m); q += __shfl_xor(q, m); }
        if (lr == 0){
            int ch = (i >> 2)*16 + lg*4 + (i & 3);
            atomicAdd(&pblk[ch], s);
            atomicAdd(&pblk[128 + ch], q);
        }
    }
}

__global__ void k_fold1(const float* __restrict__ g1a, const float* __restrict__ bt1a,
                        const float* __restrict__ W1b, const float* __restrict__ b1b,
                        float* __restrict__ pblk, float fE)
{
    __shared__ float tS[128];
    int tid = threadIdx.x;
    if (tid < 128){
        float m = pblk[tid] * fE;
        float q = pblk[128 + tid] * fE;
        float v = fmaxf(q - m*m, 0.f);
        float s = g1a[tid] * rsqrtf(v + EPSBN);
        float t = bt1a[tid] - m*s;
        pblk[512 + tid] = s;
        pblk[640 + tid] = t;
        tS[tid] = t;
    }
    __syncthreads();
    if (tid < 64){
        float acc = b1b[tid];
        for (int k = 0; k < 128; k++) acc = fmaf(tS[k], W1b[k*64 + tid], acc);
        pblk[768 + tid] = acc;
    }
}

__global__ __launch_bounds__(256) void k_pass2(
    const u16* __restrict__ xb, const int2* __restrict__ ep,
    const float* __restrict__ W1a, const float* __restrict__ b1a,
    const float* __restrict__ W1b,
    float* __restrict__ pblk, float* __restrict__ agg, int E, int nTiles)
{
    __shared__ u16 Wt [128*128];  // W1a^T
    __shared__ u16 Wt2[ 64*128];  // (s1a * W1b)^T  (BN1a folded)
    __shared__ u16 At [ 64*128];
    int tid = threadIdx.x;
    for (int i = tid; i < 128*128; i += 256){
        int k = i >> 7, n = i & 127;
        Wt[swz(n, k)] = (u16)f2bf1(W1a[i]);
    }
    for (int i = tid; i < 64*128; i += 256){
        int k = i >> 6, n = i & 63;
        Wt2[swz(n, k)] = (u16)f2bf1(W1b[i] * pblk[512 + k]);
    }
    __syncthreads();
    int lane = tid & 63, wave = tid >> 6;
    int lg = lane >> 4, lr = lane & 15;
    const float4* Bv = (const float4*)b1a;
    float runS[16], runQ[16];
    #pragma unroll
    for (int i = 0; i < 16; i++){ runS[i] = 0.f; runQ[i] = 0.f; }

    int t = blockIdx.x;
    Pref p;
    load_tile(p, xb, ep, t, wave, lane, E);
    for (; t < nTiles; t += gridDim.x){
        int tn = t + gridDim.x;
        Pref pn;
        if (tn < nTiles) load_tile(pn, xb, ep, tn, wave, lane, E);
        write_At(At, p, wave, lane);
        int row = wave*16 + lr;
        bf16x8 bfr[4];
        #pragma unroll
        for (int kt = 0; kt < 4; kt++)
            bfr[kt] = *(const bf16x8*)&At[swz(row, kt*32 + lg*8)];
        // GEMM-a: h1a = relu(E@W1a+b1a), write back into At (own rows only)
        #pragma unroll
        for (int mt = 0; mt < 8; mt++){
            f32x4 acc = {0.f,0.f,0.f,0.f};
            #pragma unroll
            for (int kt = 0; kt < 4; kt++){
                bf16x8 af = *(const bf16x8*)&Wt[swz(mt*16 + lr, kt*32 + lg*8)];
                acc = mfma16(af, bfr[kt], acc);
            }
            float4 bb = Bv[mt*4 + lg];
            const float* bbp = (const float*)&bb;
            us4 w;
            #pragma unroll
            for (int j = 0; j < 4; j++)
                w[j] = (u16)f2bf1(fmaxf(acc[j] + bbp[j], 0.f));
            *(us4*)&At[swz(row, mt*16 + lg*4)] = w;
        }
        // GEMM-b + segmented-max scatter
        bf16x8 br2[4];
        #pragma unroll
        for (int kt = 0; kt < 4; kt++)
            br2[kt] = *(const bf16x8*)&At[swz(row, kt*32 + lg*8)];
        bool ev = (t*64 + wave*16 + lr) < E;
        int dL = __shfl(p.dstS, (lane & 15) << 2);
        SegMasks sm = seg_masks(dL, lr);
        const float* B2p = &pblk[768];
        #pragma unroll
        for (int mt = 0; mt < 4; mt++){
            f32x4 acc = {0.f,0.f,0.f,0.f};
            #pragma unroll
            for (int kt = 0; kt < 4; kt++){
                bf16x8 af = *(const bf16x8*)&Wt2[swz(mt*16 + lr, kt*32 + lg*8)];
                acc = mfma16(af, br2[kt], acc);
            }
            #pragma unroll
            for (int j = 0; j < 4; j++){
                int ch = mt*16 + lg*4 + j;
                float h = fmaxf(acc[j] + B2p[ch], 0.f);
                if (ev){
                    runS[mt*4+j] += h;
                    runQ[mt*4+j] = fmaf(h, h, runQ[mt*4+j]);
                }
                float v = seg_max(h, sm);
                if (sm.head && ev) atomicMaxF(&agg[dL*64 + ch], v);
            }
        }
        if (tn < nTiles) p = pn;
    }
    #pragma unroll
    for (int i = 0; i < 16; i++){
        float s = runS[i], q = runQ[i];
        #pragma unroll
        for (int m = 1; m < 16; m <<= 1){ s += __shfl_xor(s, m); q += __shfl_xor(q, m); }
        if (lr == 0){
            int ch = (i >> 2)*16 + lg*4 + (i & 3);
            atomicAdd(&pblk[256 + ch], s);
            atomicAdd(&pblk[320 + ch], q);
        }
    }
}

// generic BN-stat fold for a 64-ch layer
__global__ void k_fold_st(const float* __restrict__ g, const float* __restrict__ bt,
                          float* __restrict__ pblk, float fE, int so, int qo, int os, int ot)
{
    int tid = threadIdx.x;
    if (tid < 64){
        float m = pblk[so + tid] * fE;
        float q = pblk[qo + tid] * fE;
        float v = fmaxf(q - m*m, 0.f);
        float s = g[tid] * rsqrtf(v + EPSBN);
        pblk[os + tid] = s;
        pblk[ot + tid] = bt[tid] - m*s;
    }
}

// x1 = relu(bn1b(agg) or 0) -> x1b (bf16); reset agg to -inf for pass3 reuse
__global__ void k_x1(float* __restrict__ agg, const float* __restrict__ pblk,
                     u16* __restrict__ x1b, int NF)
{
    int i = blockIdx.x*256 + threadIdx.x;
    if (i >= NF) return;
    int c = i & 63;
    float a = agg[i];
    float v = (a > -INFINITY) ? fmaf(a, pblk[832 + c], pblk[896 + c]) : 0.f;
    v = fmaxf(v, 0.f);
    x1b[i] = (u16)f2bf1(v);
    agg[i] = -INFINITY;
}

__global__ __launch_bounds__(256) void k_pass3(
    const u16* __restrict__ x1b, const int2* __restrict__ ep,
    const float* __restrict__ W2, const float* __restrict__ b2,
    float* __restrict__ pblk, float* __restrict__ agg, int E, int nTiles)
{
    __shared__ u16 Wt[64*128];
    __shared__ u16 At[64*128];
    int tid = threadIdx.x;
    for (int i = tid; i < 64*128; i += 256){
        int k = i >> 6, n = i & 63;
        Wt[swz(n, k)] = (u16)f2bf1(W2[i]);
    }
    __syncthreads();
    int lane = tid & 63, wave = tid >> 6;
    int lg = lane >> 4, lr = lane & 15;
    const float4* Bv = (const float4*)b2;
    float runS[16], runQ[16];
    #pragma unroll
    for (int i = 0; i < 16; i++){ runS[i] = 0.f; runQ[i] = 0.f; }

    int t = blockIdx.x;
    Pref p;
    load_tile(p, x1b, ep, t, wave, lane, E);
    for (; t < nTiles; t += gridDim.x){
        int tn = t + gridDim.x;
        Pref pn;
        if (tn < nTiles) load_tile(pn, x1b, ep, tn, wave, lane, E);
        write_At(At, p, wave, lane);
        int row = wave*16 + lr;
        bf16x8 bfr[4];
        #pragma unroll
        for (int kt = 0; kt < 4; kt++)
            bfr[kt] = *(const bf16x8*)&At[swz(row, kt*32 + lg*8)];
        bool ev = (t*64 + wave*16 + lr) < E;
        int dL = __shfl(p.dstS, (lane & 15) << 2);
        SegMasks sm = seg_masks(dL, lr);
        #pragma unroll
        for (int mt = 0; mt < 4; mt++){
            f32x4 acc = {0.f,0.f,0.f,0.f};
            #pragma unroll
            for (int kt = 0; kt < 4; kt++){
                bf16x8 af = *(const bf16x8*)&Wt[swz(mt*16 + lr, kt*32 + lg*8)];
                acc = mfma16(af, bfr[kt], acc);
            }
            float4 bb = Bv[mt*4 + lg];
            const float* bbp = (const float*)&bb;
            #pragma unroll
            for (int j = 0; j < 4; j++){
                int ch = mt*16 + lg*4 + j;
                float h = fmaxf(acc[j] + bbp[j], 0.f);
                if (ev){
                    runS[mt*4+j] += h;
                    runQ[mt*4+j] = fmaf(h, h, runQ[mt*4+j]);
                }
                float v = seg_max(h, sm);
                if (sm.head && ev) atomicMaxF(&agg[dL*64 + ch], v);
            }
        }
        if (tn < nTiles) p = pn;
    }
    #pragma unroll
    for (int i = 0; i < 16; i++){
        float s = runS[i], q = runQ[i];
        #pragma unroll
        for (int m = 1; m < 16; m <<= 1){ s += __shfl_xor(s, m); q += __shfl_xor(q, m); }
        if (lr == 0){
            int ch = (i >> 2)*16 + lg*4 + (i & 3);
            atomicAdd(&pblk[384 + ch], s);
            atomicAdd(&pblk[448 + ch], q);
        }
    }
}

// 256 threads = 4 groups x 64 channels; each group serially accumulates 32
// sorted nodes, flushing per graph-run -> ~200k atomics total.
#define FUSE_NODES 128
__global__ __launch_bounds__(256) void k_fuse(const float* __restrict__ agg,
                                              const u16* __restrict__ x1b,
                                              const int* __restrict__ batch,
                                              float* __restrict__ pblk, int N)
{
    int c = threadIdx.x & 63, r = threadIdx.x >> 6;
    int n0 = blockIdx.x*FUSE_NODES + r*(FUSE_NODES/4);
    if (n0 >= N) return;
    int n1 = n0 + FUSE_NODES/4; if (n1 > N) n1 = N;
    float s2c = pblk[960 + c], t2c = pblk[1024 + c];
    float gm = -INFINITY, gs = 0.f;
    int cur = batch[n0], cnt0 = 0;
    for (int n = n0; n < n1; ++n){
        int g = batch[n];
        if (g != cur){
            atomicMaxF(&pblk[1088 + cur*64 + c], gm);
            atomicAdd(&pblk[5184 + cur*64 + c], gs);
            if (c == 0) atomicAdd(&pblk[9280 + cur], (float)cnt0);
            gm = -INFINITY; gs = 0.f; cnt0 = 0; cur = g;
        }
        float a = agg[n*64 + c];
        float v = (a > -INFINITY) ? fmaf(a, s2c, t2c) : 0.f;
        v = fmaxf(v, 0.f);
        float f = bf2f(x1b[n*64 + c]) + v;
        gm = fmaxf(gm, f); gs += f; cnt0++;
    }
    atomicMaxF(&pblk[1088 + cur*64 + c], gm);
    atomicAdd(&pblk[5184 + cur*64 + c], gs);
    if (c == 0) atomicAdd(&pblk[9280 + cur], (float)cnt0);
}

__global__ void k_out(const float* __restrict__ pblk, float* __restrict__ out)
{
    int i = blockIdx.x*256 + threadIdx.x;
    if (i >= 64*128) return;
    int g = i >> 7, c = i & 127;
    float r;
    if (c < 64){
        float m = pblk[1088 + g*64 + c];
        r = (m > -INFINITY) ? m : 0.f;
    } else {
        float s = pblk[5184 + g*64 + (c - 64)];
        float n = pblk[9280 + g];
        r = s / fmaxf(n, 1.f);
    }
    out[i] = r;
}

extern "C" void kernel_launch(void* const* d_in, const int* in_sizes, int n_in,
                              void* d_out, int out_size, void* d_ws, size_t ws_size,
                              hipStream_t stream)
{
    const float* x    = (const float*)d_in[0];
    const int*   ei   = (const int*)  d_in[1];
    const int*   batch= (const int*)  d_in[2];
    const float* W1a  = (const float*)d_in[3];
    const float* b1a  = (const float*)d_in[4];
    const float* g1a  = (const float*)d_in[5];
    const float* bt1a = (const float*)d_in[6];
    const float* W1b  = (const float*)d_in[7];
    const float* b1b  = (const float*)d_in[8];
    const float* g1b  = (const float*)d_in[9];
    const float* bt1b = (const float*)d_in[10];
    const float* W2   = (const float*)d_in[11];
    const float* b2   = (const float*)d_in[12];
    const float* g2   = (const float*)d_in[13];
    const float* bt2  = (const float*)d_in[14];

    int N  = in_sizes[0] / 64;
    int E  = in_sizes[1] / 2;
    int NF = N * 64;

    char* ws = (char*)d_ws;
    size_t off = 0;
    auto alloc = [&](size_t bytes){ size_t o = off; off += (bytes + 255) & ~(size_t)255; return o; };
    u16*   xb    = (u16*)  (ws + alloc((size_t)NF*2));
    u16*   x1b   = (u16*)  (ws + alloc((size_t)NF*2));
    float* agg   = (float*)(ws + alloc((size_t)NF*4));
    float* pblk  = (float*)(ws + alloc((size_t)PB_TOT*4));
    int*   deg   = (int*)  (ws + alloc((size_t)N*4));
    int*   cursor= (int*)  (ws + alloc((size_t)N*4));
    int2*  ep    = (int2*) (ws + alloc((size_t)E*8));
    (void)ws_size;

    const int* esrc = ei;
    const int* edst = ei + E;
    int nTiles = (E + 63) / 64;
    int gPass  = nTiles < 2048 ? nTiles : 2048;
    int gElem  = (NF + 255) / 256;
    int gEdge  = (E + 255) / 256;
    float fE   = 1.f / (float)E;

    k_init   <<<gElem, 256, 0, stream>>>(x, xb, agg, pblk, deg, NF, N);
    k_hist   <<<gEdge, 256, 0, stream>>>(edst, deg, E);
    k_scan   <<<1, 1024, 0, stream>>>(deg, cursor, N);
    k_scatter<<<gEdge, 256, 0, stream>>>(esrc, edst, cursor, ep, E);
    k_pass1  <<<gPass, 256, 0, stream>>>(xb, ep, W1a, b1a, pblk, E, nTiles);
    k_fold1  <<<1, 128, 0, stream>>>(g1a, bt1a, W1b, b1b, pblk, fE);
    k_pass2  <<<gPass, 256, 0, stream>>>(xb, ep, W1a, b1a, W1b, pblk, agg, E, nTiles);
    k_fold_st<<<1, 64, 0, stream>>>(g1b, bt1b, pblk, fE, 256, 320, 832, 896);
    k_x1     <<<gElem, 256, 0, stream>>>(agg, pblk, x1b, NF);
    k_pass3  <<<gPass, 256, 0, stream>>>(x1b, ep, W2, b2, pblk, agg, E, nTiles);
    k_fold_st<<<1, 64, 0, stream>>>(g2, bt2, pblk, fE, 384, 448, 960, 1024);
    k_fuse   <<<(N + FUSE_NODES - 1)/FUSE_NODES, 256, 0, stream>>>(agg, x1b, batch, pblk, N);
    k_out    <<<32, 256, 0, stream>>>(pblk, (float*)d_out);
}

// Round 6
// 2824.414 us; speedup vs baseline: 1.0181x; 1.0181x over previous
//
#include <hip/hip_runtime.h>
#include <math.h>

// GraphNet: 2x EdgeConv (E=800k, F=H=64) + BN folded/commuted + pooling.
// R6: h1a spill. pass1 stores h1a (bf16, fragment-major) to ws; pass2 becomes
// a gather-free streaming GEMM-b (no GEMM-a recompute, 16KB LDS, coalesced
// fragment loads). Host falls back to the R5 kernels if ws_size is too small.

typedef unsigned short u16;
typedef unsigned int   u32;
typedef __bf16 bf16x8 __attribute__((ext_vector_type(8)));
typedef float  f32x4  __attribute__((ext_vector_type(4)));
typedef unsigned short us4 __attribute__((ext_vector_type(4)));

#define EPSBN 1e-5f
#define PB_TOT 9344
// pblk: 0:stS1a[128] 128:stQ1a[128] 256:stS1b 320:stQ1b 384:stS2 448:stQ2
// 512:s1a[128] 640:t1a[128] 768:b1bF[64] 832:s1b 896:t1b 960:s2 1024:t2
// 1088:gmax[4096] 5184:gsum[4096] 9280:cnt[64]

__device__ __forceinline__ u32 f2bf1(float f){
    u32 u = __float_as_uint(f);
    return (u + 0x7FFFu + ((u >> 16) & 1u)) >> 16;
}
__device__ __forceinline__ float bf2f(u16 b){
    return __uint_as_float(((u32)b) << 16);
}
__device__ __forceinline__ u32 bsub2(u32 xj, u32 xi){
    float jl = __uint_as_float(xj << 16), jh = __uint_as_float(xj & 0xFFFF0000u);
    float il = __uint_as_float(xi << 16), ih = __uint_as_float(xi & 0xFFFF0000u);
    u32 lo = f2bf1(jl - il), hi = f2bf1(jh - ih);
    return lo | (hi << 16);
}
__device__ __forceinline__ void atomicMaxF(float* a, float v){
    if (v >= 0.f) atomicMax((int*)a, __float_as_int(v));
    else          atomicMin((u32*)a, __float_as_uint(v));
}
__device__ __forceinline__ int swz(int row, int k){
    return row*128 + (k ^ ((row & 7) << 3));
}
__device__ __forceinline__ f32x4 mfma16(bf16x8 a, bf16x8 b, f32x4 c){
    return __builtin_amdgcn_mfma_f32_16x16x32_bf16(a, b, c, 0, 0, 0);
}

// Segment-run merge masks; ALL shuffles unconditional (R4 lesson).
struct SegMasks { bool head, m1, m2, m4, m8; };
__device__ __forceinline__ SegMasks seg_masks(int dL, int lr){
    int dUp = __shfl_up(dL, 1, 16);
    int d1  = __shfl_down(dL, 1, 16);
    int d2  = __shfl_down(dL, 2, 16);
    int d4  = __shfl_down(dL, 4, 16);
    int d8  = __shfl_down(dL, 8, 16);
    SegMasks s;
    s.head = (lr == 0) || (dUp != dL);
    s.m1 = (lr + 1 < 16) && (d1 == dL);
    s.m2 = (lr + 2 < 16) && (d2 == dL);
    s.m4 = (lr + 4 < 16) && (d4 == dL);
    s.m8 = (lr + 8 < 16) && (d8 == dL);
    return s;
}
__device__ __forceinline__ float seg_max(float v, const SegMasks& s){
    float t1 = __shfl_down(v, 1, 16); if (s.m1) v = fmaxf(v, t1);
    float t2 = __shfl_down(v, 2, 16); if (s.m2) v = fmaxf(v, t2);
    float t4 = __shfl_down(v, 4, 16); if (s.m4) v = fmaxf(v, t4);
    float t8 = __shfl_down(v, 8, 16); if (s.m8) v = fmaxf(v, t8);
    return v;
}

struct Pref { uint4 xi0, xi1, xj0, xj1; int dstS; };
__device__ __forceinline__ void load_tile(Pref& p, const u16* __restrict__ xb,
                                          const int2* __restrict__ ep,
                                          int t, int wave, int lane, int E){
    int eS = t*64 + wave*16 + (lane >> 2);
    if (eS < E){
        int2 sd = ep[eS];
        p.dstS = sd.y;
        int part = lane & 3;
        const uint4* pi = (const uint4*)(xb + (size_t)sd.y*64 + part*16);
        const uint4* pj = (const uint4*)(xb + (size_t)sd.x*64 + part*16);
        p.xi0 = pi[0]; p.xi1 = pi[1];
        p.xj0 = pj[0]; p.xj1 = pj[1];
    } else {
        uint4 z; z.x = z.y = z.z = z.w = 0u;
        p.xi0 = p.xi1 = p.xj0 = p.xj1 = z;
        p.dstS = -2;
    }
}
__device__ __forceinline__ void write_At(u16* At, const Pref& p, int wave, int lane){
    int part = lane & 3;
    int arow = wave*16 + (lane >> 2);
    *(uint4*)&At[swz(arow, part*16)]     = p.xi0;
    *(uint4*)&At[swz(arow, part*16+8)]   = p.xi1;
    uint4 e0, e1;
    e0.x = bsub2(p.xj0.x, p.xi0.x); e0.y = bsub2(p.xj0.y, p.xi0.y);
    e0.z = bsub2(p.xj0.z, p.xi0.z); e0.w = bsub2(p.xj0.w, p.xi0.w);
    e1.x = bsub2(p.xj1.x, p.xi1.x); e1.y = bsub2(p.xj1.y, p.xi1.y);
    e1.z = bsub2(p.xj1.z, p.xi1.z); e1.w = bsub2(p.xj1.w, p.xi1.w);
    *(uint4*)&At[swz(arow, 64+part*16)]   = e0;
    *(uint4*)&At[swz(arow, 64+part*16+8)] = e1;
}

__global__ void k_init(const float* __restrict__ x, u16* __restrict__ xb,
                       float* __restrict__ agg,
                       float* __restrict__ pblk, int* __restrict__ deg,
                       int NF, int N){
    int i = blockIdx.x*256 + threadIdx.x;
    if (i < NF){
        xb[i] = (u16)f2bf1(x[i]);
        agg[i] = -INFINITY;
    }
    if (i < N) deg[i] = 0;
    if (i < PB_TOT){
        pblk[i] = (i >= 1088 && i < 5184) ? -INFINITY : 0.f;
    }
}

__global__ void k_hist(const int* __restrict__ edst, int* __restrict__ deg, int E){
    int e = blockIdx.x*256 + threadIdx.x;
    if (e < E) atomicAdd(&deg[edst[e]], 1);
}

__global__ __launch_bounds__(1024) void k_scan(const int* __restrict__ deg,
                                               int* __restrict__ cursor, int N){
    __shared__ int buf[1024];
    __shared__ int carry;
    int tid = threadIdx.x;
    if (tid == 0) carry = 0;
    __syncthreads();
    for (int base = 0; base < N; base += 1024){
        int i = base + tid;
        int v = (i < N) ? deg[i] : 0;
        buf[tid] = v;
        __syncthreads();
        #pragma unroll
        for (int s = 1; s < 1024; s <<= 1){
            int a = (tid >= s) ? buf[tid - s] : 0;
            __syncthreads();
            buf[tid] += a;
            __syncthreads();
        }
        int inc = buf[tid] + carry;
        if (i < N) cursor[i] = inc - v;
        __syncthreads();
        if (tid == 1023) carry = inc;
        __syncthreads();
    }
}

__global__ void k_scatter(const int* __restrict__ esrc, const int* __restrict__ edst,
                          int* __restrict__ cursor, int2* __restrict__ ep, int E){
    int e = blockIdx.x*256 + threadIdx.x;
    if (e < E){
        int d = edst[e];
        int pos = atomicAdd(&cursor[d], 1);
        ep[pos] = make_int2(esrc[e], d);
    }
}

// ---------- spill path: pass1 computes h1a + stats, stores fragment-major ----
__global__ __launch_bounds__(256) void k_pass1s(
    const u16* __restrict__ xb, const int2* __restrict__ ep,
    const float* __restrict__ W1a, const float* __restrict__ b1a,
    float* __restrict__ pblk, u16* __restrict__ h1a, int E, int nTiles)
{
    __shared__ u16 Wt[128*128];
    __shared__ u16 At[64*128];
    int tid = threadIdx.x;
    for (int i = tid; i < 128*128; i += 256){
        int k = i >> 7, n = i & 127;
        Wt[swz(n, k)] = (u16)f2bf1(W1a[i]);
    }
    __syncthreads();
    int lane = tid & 63, wave = tid >> 6;
    int lg = lane >> 4, lr = lane & 15;
    const float4* Bv = (const float4*)b1a;
    float runS[32], runQ[32];
    #pragma unroll
    for (int i = 0; i < 32; i++){ runS[i] = 0.f; runQ[i] = 0.f; }

    int t = blockIdx.x;
    Pref p;
    load_tile(p, xb, ep, t, wave, lane, E);
    for (; t < nTiles; t += gridDim.x){
        int tn = t + gridDim.x;
        Pref pn;
        if (tn < nTiles) load_tile(pn, xb, ep, tn, wave, lane, E);
        write_At(At, p, wave, lane);
        int row = wave*16 + lr;
        bf16x8 bfr[4];
        #pragma unroll
        for (int kt = 0; kt < 4; kt++)
            bfr[kt] = *(const bf16x8*)&At[swz(row, kt*32 + lg*8)];
        bool ev = (t*64 + wave*16 + lr) < E;
        #pragma unroll
        for (int mt = 0; mt < 8; mt++){
            f32x4 acc = {0.f,0.f,0.f,0.f};
            #pragma unroll
            for (int kt = 0; kt < 4; kt++){
                bf16x8 af = *(const bf16x8*)&Wt[swz(mt*16 + lr, kt*32 + lg*8)];
                acc = mfma16(af, bfr[kt], acc);
            }
            float4 bb = Bv[mt*4 + lg];
            const float* bbp = (const float*)&bb;
            us4 w;
            #pragma unroll
            for (int j = 0; j < 4; j++){
                float h = fmaxf(acc[j] + bbp[j], 0.f);
                if (ev){
                    runS[mt*4+j] += h;
                    runQ[mt*4+j] = fmaf(h, h, runQ[mt*4+j]);
                }
                w[j] = (u16)f2bf1(h);
            }
            *(us4*)&At[swz(row, mt*16 + lg*4)] = w;
        }
        // spill h1a fragment-major: [t][wave][kt][lane] x 8ch (16B, coalesced)
        #pragma unroll
        for (int kt = 0; kt < 4; kt++){
            uint4 v = *(const uint4*)&At[swz(row, kt*32 + lg*8)];
            *(uint4*)(h1a + ((((size_t)t*4 + wave)*4 + kt)*64 + lane)*8) = v;
        }
        if (tn < nTiles) p = pn;
    }
    #pragma unroll
    for (int i = 0; i < 32; i++){
        float s = runS[i], q = runQ[i];
        #pragma unroll
        for (int m = 1; m < 16; m <<= 1){ s += __shfl_xor(s, m); q += __shfl_xor(q, m); }
        if (lr == 0){
            int ch = (i >> 2)*16 + lg*4 + (i & 3);
            atomicAdd(&pblk[ch], s);
            atomicAdd(&pblk[128 + ch], q);
        }
    }
}

// spill path pass2: stream h1a fragments, GEMM-b only, seg-max scatter.
__global__ __launch_bounds__(256) void k_pass2s(
    const u16* __restrict__ h1a, const int2* __restrict__ ep,
    const float* __restrict__ W1b,
    float* __restrict__ pblk, float* __restrict__ agg, int E, int nTiles)
{
    __shared__ u16 Wt2[64*128];   // (s1a * W1b)^T swizzled
    int tid = threadIdx.x;
    for (int i = tid; i < 64*128; i += 256){
        int k = i >> 6, n = i & 63;
        Wt2[swz(n, k)] = (u16)f2bf1(W1b[i] * pblk[512 + k]);
    }
    __syncthreads();
    int lane = tid & 63, wave = tid >> 6;
    int lg = lane >> 4, lr = lane & 15;
    float runS[16], runQ[16], b2r[16];
    #pragma unroll
    for (int i = 0; i < 16; i++){
        runS[i] = 0.f; runQ[i] = 0.f;
        b2r[i] = pblk[768 + (i >> 2)*16 + lg*4 + (i & 3)];
    }
    const int* epi = (const int*)ep;

    for (int t = blockIdx.x; t < nTiles; t += gridDim.x){
        bf16x8 br2[4];
        #pragma unroll
        for (int kt = 0; kt < 4; kt++)
            br2[kt] = *(const bf16x8*)(h1a + ((((size_t)t*4 + wave)*4 + kt)*64 + lane)*8);
        int eV = t*64 + wave*16 + lr;
        bool ev = eV < E;
        int dL = ev ? epi[2*eV + 1] : -2;
        SegMasks sm = seg_masks(dL, lr);
        #pragma unroll
        for (int mt = 0; mt < 4; mt++){
            f32x4 acc = {0.f,0.f,0.f,0.f};
            #pragma unroll
            for (int kt = 0; kt < 4; kt++){
                bf16x8 af = *(const bf16x8*)&Wt2[swz(mt*16 + lr, kt*32 + lg*8)];
                acc = mfma16(af, br2[kt], acc);
            }
            #pragma unroll
            for (int j = 0; j < 4; j++){
                int ch = mt*16 + lg*4 + j;
                float h = fmaxf(acc[j] + b2r[mt*4+j], 0.f);
                if (ev){
                    runS[mt*4+j] += h;
                    runQ[mt*4+j] = fmaf(h, h, runQ[mt*4+j]);
                }
                float v = seg_max(h, sm);
                if (sm.head && ev) atomicMaxF(&agg[dL*64 + ch], v);
            }
        }
    }
    #pragma unroll
    for (int i = 0; i < 16; i++){
        float s = runS[i], q = runQ[i];
        #pragma unroll
        for (int m = 1; m < 16; m <<= 1){ s += __shfl_xor(s, m); q += __shfl_xor(q, m); }
        if (lr == 0){
            int ch = (i >> 2)*16 + lg*4 + (i & 3);
            atomicAdd(&pblk[256 + ch], s);
            atomicAdd(&pblk[320 + ch], q);
        }
    }
}

// ---------- fallback path (R5 kernels) ----------
__global__ __launch_bounds__(256) void k_pass1(
    const u16* __restrict__ xb, const int2* __restrict__ ep,
    const float* __restrict__ W1a, const float* __restrict__ b1a,
    float* __restrict__ pblk, int E, int nTiles)
{
    __shared__ u16 Wt[128*128];
    __shared__ u16 At[64*128];
    int tid = threadIdx.x;
    for (int i = tid; i < 128*128; i += 256){
        int k = i >> 7, n = i & 127;
        Wt[swz(n, k)] = (u16)f2bf1(W1a[i]);
    }
    __syncthreads();
    int lane = tid & 63, wave = tid >> 6;
    int lg = lane >> 4, lr = lane & 15;
    const float4* Bv = (const float4*)b1a;
    float runS[32], runQ[32];
    #pragma unroll
    for (int i = 0; i < 32; i++){ runS[i] = 0.f; runQ[i] = 0.f; }
    int t = blockIdx.x;
    Pref p;
    load_tile(p, xb, ep, t, wave, lane, E);
    for (; t < nTiles; t += gridDim.x){
        int tn = t + gridDim.x;
        Pref pn;
        if (tn < nTiles) load_tile(pn, xb, ep, tn, wave, lane, E);
        write_At(At, p, wave, lane);
        int row = wave*16 + lr;
        bf16x8 bfr[4];
        #pragma unroll
        for (int kt = 0; kt < 4; kt++)
            bfr[kt] = *(const bf16x8*)&At[swz(row, kt*32 + lg*8)];
        bool ev = (t*64 + wave*16 + lr) < E;
        #pragma unroll
        for (int mt = 0; mt < 8; mt++){
            f32x4 acc = {0.f,0.f,0.f,0.f};
            #pragma unroll
            for (int kt = 0; kt < 4; kt++){
                bf16x8 af = *(const bf16x8*)&Wt[swz(mt*16 + lr, kt*32 + lg*8)];
                acc = mfma16(af, bfr[kt], acc);
            }
            if (ev){
                float4 bb = Bv[mt*4 + lg];
                const float* bbp = (const float*)&bb;
                #pragma unroll
                for (int j = 0; j < 4; j++){
                    float h = fmaxf(acc[j] + bbp[j], 0.f);
                    runS[mt*4+j] += h;
                    runQ[mt*4+j] = fmaf(h, h, runQ[mt*4+j]);
                }
            }
        }
        if (tn < nTiles) p = pn;
    }
    #pragma unroll
    for (int i = 0; i < 32; i++){
        float s = runS[i], q = runQ[i];
        #pragma unroll
        for (int m = 1; m < 16; m <<= 1){ s += __shfl_xor(s, m); q += __shfl_xor(q, m); }
        if (lr == 0){
            int ch = (i >> 2)*16 + lg*4 + (i & 3);
            atomicAdd(&pblk[ch], s);
            atomicAdd(&pblk[128 + ch], q);
        }
    }
}

__global__ __launch_bounds__(256) void k_pass2(
    const u16* __restrict__ xb, const int2* __restrict__ ep,
    const float* __restrict__ W1a, const float* __restrict__ b1a,
    const float* __restrict__ W1b,
    float* __restrict__ pblk, float* __restrict__ agg, int E, int nTiles)
{
    __shared__ u16 Wt [128*128];
    __shared__ u16 Wt2[ 64*128];
    __shared__ u16 At [ 64*128];
    int tid = threadIdx.x;
    for (int i = tid; i < 128*128; i += 256){
        int k = i >> 7, n = i & 127;
        Wt[swz(n, k)] = (u16)f2bf1(W1a[i]);
    }
    for (int i = tid; i < 64*128; i += 256){
        int k = i >> 6, n = i & 63;
        Wt2[swz(n, k)] = (u16)f2bf1(W1b[i] * pblk[512 + k]);
    }
    __syncthreads();
    int lane = tid & 63, wave = tid >> 6;
    int lg = lane >> 4, lr = lane & 15;
    const float4* Bv = (const float4*)b1a;
    float runS[16], runQ[16];
    #pragma unroll
    for (int i = 0; i < 16; i++){ runS[i] = 0.f; runQ[i] = 0.f; }
    int t = blockIdx.x;
    Pref p;
    load_tile(p, xb, ep, t, wave, lane, E);
    for (; t < nTiles; t += gridDim.x){
        int tn = t + gridDim.x;
        Pref pn;
        if (tn < nTiles) load_tile(pn, xb, ep, tn, wave, lane, E);
        write_At(At, p, wave, lane);
        int row = wave*16 + lr;
        bf16x8 bfr[4];
        #pragma unroll
        for (int kt = 0; kt < 4; kt++)
            bfr[kt] = *(const bf16x8*)&At[swz(row, kt*32 + lg*8)];
        #pragma unroll
        for (int mt = 0; mt < 8; mt++){
            f32x4 acc = {0.f,0.f,0.f,0.f};
            #pragma unroll
            for (int kt = 0; kt < 4; kt++){
                bf16x8 af = *(const bf16x8*)&Wt[swz(mt*16 + lr, kt*32 + lg*8)];
                acc = mfma16(af, bfr[kt], acc);
            }
            float4 bb = Bv[mt*4 + lg];
            const float* bbp = (const float*)&bb;
            us4 w;
            #pragma unroll
            for (int j = 0; j < 4; j++)
                w[j] = (u16)f2bf1(fmaxf(acc[j] + bbp[j], 0.f));
            *(us4*)&At[swz(row, mt*16 + lg*4)] = w;
        }
        bf16x8 br2[4];
        #pragma unroll
        for (int kt = 0; kt < 4; kt++)
            br2[kt] = *(const bf16x8*)&At[swz(row, kt*32 + lg*8)];
        bool ev = (t*64 + wave*16 + lr) < E;
        int dL = __shfl(p.dstS, (lane & 15) << 2);
        SegMasks sm = seg_masks(dL, lr);
        const float* B2p = &pblk[768];
        #pragma unroll
        for (int mt = 0; mt < 4; mt++){
            f32x4 acc = {0.f,0.f,0.f,0.f};
            #pragma unroll
            for (int kt = 0; kt < 4; kt++){
                bf16x8 af = *(const bf16x8*)&Wt2[swz(mt*16 + lr, kt*32 + lg*8)];
                acc = mfma16(af, br2[kt], acc);
            }
            #pragma unroll
            for (int j = 0; j < 4; j++){
                int ch = mt*16 + lg*4 + j;
                float h = fmaxf(acc[j] + B2p[ch], 0.f);
                if (ev){
                    runS[mt*4+j] += h;
                    runQ[mt*4+j] = fmaf(h, h, runQ[mt*4+j]);
                }
                float v = seg_max(h, sm);
                if (sm.head && ev) atomicMaxF(&agg[dL*64 + ch], v);
            }
        }
        if (tn < nTiles) p = pn;
    }
    #pragma unroll
    for (int i = 0; i < 16; i++){
        float s = runS[i], q = runQ[i];
        #pragma unroll
        for (int m = 1; m < 16; m <<= 1){ s += __shfl_xor(s, m); q += __shfl_xor(q, m); }
        if (lr == 0){
            int ch = (i >> 2)*16 + lg*4 + (i & 3);
            atomicAdd(&pblk[256 + ch], s);
            atomicAdd(&pblk[320 + ch], q);
        }
    }
}

__global__ void k_fold1(const float* __restrict__ g1a, const float* __restrict__ bt1a,
                        const float* __restrict__ W1b, const float* __restrict__ b1b,
                        float* __restrict__ pblk, float fE)
{
    __shared__ float tS[128];
    int tid = threadIdx.x;
    if (tid < 128){
        float m = pblk[tid] * fE;
        float q = pblk[128 + tid] * fE;
        float v = fmaxf(q - m*m, 0.f);
        float s = g1a[tid] * rsqrtf(v + EPSBN);
        float t = bt1a[tid] - m*s;
        pblk[512 + tid] = s;
        pblk[640 + tid] = t;
        tS[tid] = t;
    }
    __syncthreads();
    if (tid < 64){
        float acc = b1b[tid];
        for (int k = 0; k < 128; k++) acc = fmaf(tS[k], W1b[k*64 + tid], acc);
        pblk[768 + tid] = acc;
    }
}

__global__ void k_fold_st(const float* __restrict__ g, const float* __restrict__ bt,
                          float* __restrict__ pblk, float fE, int so, int qo, int os, int ot)
{
    int tid = threadIdx.x;
    if (tid < 64){
        float m = pblk[so + tid] * fE;
        float q = pblk[qo + tid] * fE;
        float v = fmaxf(q - m*m, 0.f);
        float s = g[tid] * rsqrtf(v + EPSBN);
        pblk[os + tid] = s;
        pblk[ot + tid] = bt[tid] - m*s;
    }
}

__global__ void k_x1(float* __restrict__ agg, const float* __restrict__ pblk,
                     u16* __restrict__ x1b, int NF)
{
    int i = blockIdx.x*256 + threadIdx.x;
    if (i >= NF) return;
    int c = i & 63;
    float a = agg[i];
    float v = (a > -INFINITY) ? fmaf(a, pblk[832 + c], pblk[896 + c]) : 0.f;
    v = fmaxf(v, 0.f);
    x1b[i] = (u16)f2bf1(v);
    agg[i] = -INFINITY;
}

__global__ __launch_bounds__(256) void k_pass3(
    const u16* __restrict__ x1b, const int2* __restrict__ ep,
    const float* __restrict__ W2, const float* __restrict__ b2,
    float* __restrict__ pblk, float* __restrict__ agg, int E, int nTiles)
{
    __shared__ u16 Wt[64*128];
    __shared__ u16 At[64*128];
    int tid = threadIdx.x;
    for (int i = tid; i < 64*128; i += 256){
        int k = i >> 6, n = i & 63;
        Wt[swz(n, k)] = (u16)f2bf1(W2[i]);
    }
    __syncthreads();
    int lane = tid & 63, wave = tid >> 6;
    int lg = lane >> 4, lr = lane & 15;
    const float4* Bv = (const float4*)b2;
    float runS[16], runQ[16];
    #pragma unroll
    for (int i = 0; i < 16; i++){ runS[i] = 0.f; runQ[i] = 0.f; }
    int t = blockIdx.x;
    Pref p;
    load_tile(p, x1b, ep, t, wave, lane, E);
    for (; t < nTiles; t += gridDim.x){
        int tn = t + gridDim.x;
        Pref pn;
        if (tn < nTiles) load_tile(pn, x1b, ep, tn, wave, lane, E);
        write_At(At, p, wave, lane);
        int row = wave*16 + lr;
        bf16x8 bfr[4];
        #pragma unroll
        for (int kt = 0; kt < 4; kt++)
            bfr[kt] = *(const bf16x8*)&At[swz(row, kt*32 + lg*8)];
        bool ev = (t*64 + wave*16 + lr) < E;
        int dL = __shfl(p.dstS, (lane & 15) << 2);
        SegMasks sm = seg_masks(dL, lr);
        #pragma unroll
        for (int mt = 0; mt < 4; mt++){
            f32x4 acc = {0.f,0.f,0.f,0.f};
            #pragma unroll
            for (int kt = 0; kt < 4; kt++){
                bf16x8 af = *(const bf16x8*)&Wt[swz(mt*16 + lr, kt*32 + lg*8)];
                acc = mfma16(af, bfr[kt], acc);
            }
            float4 bb = Bv[mt*4 + lg];
            const float* bbp = (const float*)&bb;
            #pragma unroll
            for (int j = 0; j < 4; j++){
                int ch = mt*16 + lg*4 + j;
                float h = fmaxf(acc[j] + bbp[j], 0.f);
                if (ev){
                    runS[mt*4+j] += h;
                    runQ[mt*4+j] = fmaf(h, h, runQ[mt*4+j]);
                }
                float v = seg_max(h, sm);
                if (sm.head && ev) atomicMaxF(&agg[dL*64 + ch], v);
            }
        }
        if (tn < nTiles) p = pn;
    }
    #pragma unroll
    for (int i = 0; i < 16; i++){
        float s = runS[i], q = runQ[i];
        #pragma unroll
        for (int m = 1; m < 16; m <<= 1){ s += __shfl_xor(s, m); q += __shfl_xor(q, m); }
        if (lr == 0){
            int ch = (i >> 2)*16 + lg*4 + (i & 3);
            atomicAdd(&pblk[384 + ch], s);
            atomicAdd(&pblk[448 + ch], q);
        }
    }
}

#define FUSE_NODES 128
__global__ __launch_bounds__(256) void k_fuse(const float* __restrict__ agg,
                                              const u16* __restrict__ x1b,
                                              const int* __restrict__ batch,
                                              float* __restrict__ pblk, int N)
{
    int c = threadIdx.x & 63, r = threadIdx.x >> 6;
    int n0 = blockIdx.x*FUSE_NODES + r*(FUSE_NODES/4);
    if (n0 >= N) return;
    int n1 = n0 + FUSE_NODES/4; if (n1 > N) n1 = N;
    float s2c = pblk[960 + c], t2c = pblk[1024 + c];
    float gm = -INFINITY, gs = 0.f;
    int cur = batch[n0], cnt0 = 0;
    for (int n = n0; n < n1; ++n){
        int g = batch[n];
        if (g != cur){
            atomicMaxF(&pblk[1088 + cur*64 + c], gm);
            atomicAdd(&pblk[5184 + cur*64 + c], gs);
            if (c == 0) atomicAdd(&pblk[9280 + cur], (float)cnt0);
            gm = -INFINITY; gs = 0.f; cnt0 = 0; cur = g;
        }
        float a = agg[n*64 + c];
        float v = (a > -INFINITY) ? fmaf(a, s2c, t2c) : 0.f;
        v = fmaxf(v, 0.f);
        float f = bf2f(x1b[n*64 + c]) + v;
        gm = fmaxf(gm, f); gs += f; cnt0++;
    }
    atomicMaxF(&pblk[1088 + cur*64 + c], gm);
    atomicAdd(&pblk[5184 + cur*64 + c], gs);
    if (c == 0) atomicAdd(&pblk[9280 + cur], (float)cnt0);
}

__global__ void k_out(const float* __restrict__ pblk, float* __restrict__ out)
{
    int i = blockIdx.x*256 + threadIdx.x;
    if (i >= 64*128) return;
    int g = i >> 7, c = i & 127;
    float r;
    if (c < 64){
        float m = pblk[1088 + g*64 + c];
        r = (m > -INFINITY) ? m : 0.f;
    } else {
        float s = pblk[5184 + g*64 + (c - 64)];
        float n = pblk[9280 + g];
        r = s / fmaxf(n, 1.f);
    }
    out[i] = r;
}

extern "C" void kernel_launch(void* const* d_in, const int* in_sizes, int n_in,
                              void* d_out, int out_size, void* d_ws, size_t ws_size,
                              hipStream_t stream)
{
    const float* x    = (const float*)d_in[0];
    const int*   ei   = (const int*)  d_in[1];
    const int*   batch= (const int*)  d_in[2];
    const float* W1a  = (const float*)d_in[3];
    const float* b1a  = (const float*)d_in[4];
    const float* g1a  = (const float*)d_in[5];
    const float* bt1a = (const float*)d_in[6];
    const float* W1b  = (const float*)d_in[7];
    const float* b1b  = (const float*)d_in[8];
    const float* g1b  = (const float*)d_in[9];
    const float* bt1b = (const float*)d_in[10];
    const float* W2   = (const float*)d_in[11];
    const float* b2   = (const float*)d_in[12];
    const float* g2   = (const float*)d_in[13];
    const float* bt2  = (const float*)d_in[14];

    int N  = in_sizes[0] / 64;
    int E  = in_sizes[1] / 2;
    int NF = N * 64;
    int nTiles = (E + 63) / 64;

    char* ws = (char*)d_ws;
    size_t off = 0;
    auto alloc = [&](size_t bytes){ size_t o = off; off += (bytes + 255) & ~(size_t)255; return o; };
    u16*   xb    = (u16*)  (ws + alloc((size_t)NF*2));
    u16*   x1b   = (u16*)  (ws + alloc((size_t)NF*2));
    float* agg   = (float*)(ws + alloc((size_t)NF*4));
    float* pblk  = (float*)(ws + alloc((size_t)PB_TOT*4));
    int*   deg   = (int*)  (ws + alloc((size_t)N*4));
    int*   cursor= (int*)  (ws + alloc((size_t)N*4));
    int2*  ep    = (int2*) (ws + alloc((size_t)E*8));
    u16*   h1a   = (u16*)  (ws + alloc((size_t)nTiles*64*128*2));
    bool spill = (ws_size >= off);   // h1a is the tail allocation

    const int* esrc = ei;
    const int* edst = ei + E;
    int gPass  = nTiles < 2048 ? nTiles : 2048;
    int gElem  = (NF + 255) / 256;
    int gEdge  = (E + 255) / 256;
    float fE   = 1.f / (float)E;

    k_init   <<<gElem, 256, 0, stream>>>(x, xb, agg, pblk, deg, NF, N);
    k_hist   <<<gEdge, 256, 0, stream>>>(edst, deg, E);
    k_scan   <<<1, 1024, 0, stream>>>(deg, cursor, N);
    k_scatter<<<gEdge, 256, 0, stream>>>(esrc, edst, cursor, ep, E);
    if (spill){
        k_pass1s<<<gPass, 256, 0, stream>>>(xb, ep, W1a, b1a, pblk, h1a, E, nTiles);
        k_fold1 <<<1, 128, 0, stream>>>(g1a, bt1a, W1b, b1b, pblk, fE);
        k_pass2s<<<gPass, 256, 0, stream>>>(h1a, ep, W1b, pblk, agg, E, nTiles);
    } else {
        k_pass1 <<<gPass, 256, 0, stream>>>(xb, ep, W1a, b1a, pblk, E, nTiles);
        k_fold1 <<<1, 128, 0, stream>>>(g1a, bt1a, W1b, b1b, pblk, fE);
        k_pass2 <<<gPass, 256, 0, stream>>>(xb, ep, W1a, b1a, W1b, pblk, agg, E, nTiles);
    }
    k_fold_st<<<1, 64, 0, stream>>>(g1b, bt1b, pblk, fE, 256, 320, 832, 896);
    k_x1     <<<gElem, 256, 0, stream>>>(agg, pblk, x1b, NF);
    k_pass3  <<<gPass, 256, 0, stream>>>(x1b, ep, W2, b2, pblk, agg, E, nTiles);
    k_fold_st<<<1, 64, 0, stream>>>(g2, bt2, pblk, fE, 384, 448, 960, 1024);
    k_fuse   <<<(N + FUSE_NODES - 1)/FUSE_NODES, 256, 0, stream>>>(agg, x1b, batch, pblk, N);
    k_out    <<<32, 256, 0, stream>>>(pblk, (float*)d_out);
}